// Round 1
// 451.714 us; speedup vs baseline: 1.0159x; 1.0159x over previous
//
#include <hip/hip_runtime.h>
#include <hip/hip_bf16.h>
#include <stdint.h>

#define NN 8192
#define MM 128
#define EPSF 1e-4f
#define SHIFT 30.0f

typedef __bf16 bf16x8 __attribute__((ext_vector_type(8)));
typedef __bf16 bf16x4 __attribute__((ext_vector_type(4)));
typedef float floatx4 __attribute__((ext_vector_type(4)));

// Fire-and-forget 16B global->LDS load, used purely as an L2/L3-warming
// prefetch for label (dest contents are garbage by design; nobody reads it).
// Zero VGPR cost, zero ALU, no waitcnt ever needed on it.
__device__ __forceinline__ void pf16(const float* g, void* lds) {
    __builtin_amdgcn_global_load_lds(
        (__attribute__((address_space(1))) void*)(uintptr_t)g,
        (__attribute__((address_space(3))) void*)(uint32_t)(uintptr_t)lds,
        16, 0, 0);
}

// fp32 -> bf16 conversion of out1 & out2 (blockIdx.y selects tensor).
// Also zeroes the sums buffer and d_out (replaces two hipMemsetAsync nodes).
__global__ void convert_kernel(const float* __restrict__ in0,
                               const float* __restrict__ in1,
                               __bf16* __restrict__ o0,
                               __bf16* __restrict__ o1,
                               float* __restrict__ sums,
                               float* __restrict__ out) {
    const float* in = blockIdx.y ? in1 : in0;
    __bf16* op = blockIdx.y ? o1 : o0;
    int i = (blockIdx.x * blockDim.x + threadIdx.x) * 4;
    float4 v = *reinterpret_cast<const float4*>(in + i);
    bf16x4 o = { (__bf16)v.x, (__bf16)v.y, (__bf16)v.z, (__bf16)v.w };
    *reinterpret_cast<bf16x4*>(op + i) = o;
    if (blockIdx.y == 0) {
        if (blockIdx.x < 16) {   // 16 blocks * 256 thr * 4 floats = 2*NN
            floatx4 z = {0.f, 0.f, 0.f, 0.f};
            *reinterpret_cast<floatx4*>(sums + (blockIdx.x * 256 + threadIdx.x) * 4) = z;
        }
        if (blockIdx.x == 16 && threadIdx.x == 0) *out = 0.f;
    }
}

#define LOAD_A(dst, ptr)                                                   \
    do {                                                                   \
        dst[0] = *reinterpret_cast<const bf16x8*>((ptr) + 0);              \
        dst[1] = *reinterpret_cast<const bf16x8*>((ptr) + 32);             \
        dst[2] = *reinterpret_cast<const bf16x8*>((ptr) + 64);             \
        dst[3] = *reinterpret_cast<const bf16x8*>((ptr) + 96);             \
    } while (0)

// ONE pass over S = A @ B^T producing BOTH row sums and col sums of
// exp(S-SHIFT).  Additionally streams the 256MB label matrix through
// L2/L3 as a prefetch (overlaps the 41us of label HBM time under this
// kernel's compute; label == Infinity Cache capacity, so loss_kernel's
// label reads become L3 hits).  Prefetch issued AFTER the b-loads so the
// compiler's vmcnt wait for b does not drain the prefetch queue.
__global__ __launch_bounds__(256)
void sums_kernel(const __bf16* __restrict__ A, const __bf16* __restrict__ B,
                 const float* __restrict__ label, float* __restrict__ sums) {
    __shared__ alignas(16) char pfbuf[1024];   // garbage sink for prefetch
    const int tid = threadIdx.x;
    const int w = tid >> 6, lane = tid & 63, q = lane >> 4, ln = lane & 15;
    const int i0 = blockIdx.y * 128 + w * 32;   // 32 rows per wave
    const int jbase = blockIdx.x * 512;         // 512 cols per block
    const int bid = blockIdx.y * gridDim.x + blockIdx.x;        // 0..1023
    const float* pfb = label + (size_t)bid * 65536 + w * 2048 + lane * 4;

    const floatx4 accInit = {-SHIFT, -SHIFT, -SHIFT, -SHIFT};

    bf16x8 a[2][4];
    #pragma unroll
    for (int rg = 0; rg < 2; ++rg)
        LOAD_A(a[rg], A + (size_t)(i0 + rg * 16 + ln) * MM + q * 8);

    float p[2][4] = {{0.f, 0.f, 0.f, 0.f}, {0.f, 0.f, 0.f, 0.f}};

    for (int js = 0; js < 8; ++js) {
        const int j0 = jbase + js * 64;
        bf16x8 b[4][4];
        #pragma unroll
        for (int cg = 0; cg < 4; ++cg)
            LOAD_A(b[cg], B + (size_t)(j0 + cg * 16 + ln) * MM + q * 8);
        // label prefetch: 8 x 1KB per wave per js -> 256KB per block total
        #pragma unroll
        for (int u = 0; u < 8; ++u)
            pf16(pfb + js * 8192 + u * 256, pfbuf);
        #pragma unroll
        for (int cg = 0; cg < 4; ++cg) {
            floatx4 acc0 = accInit, acc1 = accInit;
            #pragma unroll
            for (int k = 0; k < 4; ++k) {
                acc0 = __builtin_amdgcn_mfma_f32_16x16x32_bf16(a[0][k], b[cg][k], acc0, 0, 0, 0);
                acc1 = __builtin_amdgcn_mfma_f32_16x16x32_bf16(a[1][k], b[cg][k], acc1, 0, 0, 0);
            }
            float e0[4], e1[4];
            #pragma unroll
            for (int r = 0; r < 4; ++r) {
                e0[r] = __expf(acc0[r]);
                e1[r] = __expf(acc1[r]);
                p[0][r] += e0[r];
                p[1][r] += e1[r];
            }
            float c = ((e0[0] + e0[1]) + (e0[2] + e0[3])) +
                      ((e1[0] + e1[1]) + (e1[2] + e1[3]));
            c += __shfl_xor(c, 16);
            c += __shfl_xor(c, 32);
            if (q == 0) atomicAdd(&sums[NN + j0 + cg * 16 + ln], c);
        }
    }

    #pragma unroll
    for (int m = 1; m <= 8; m <<= 1)
        #pragma unroll
        for (int rg = 0; rg < 2; ++rg)
            #pragma unroll
            for (int r = 0; r < 4; ++r)
                p[rg][r] += __shfl_xor(p[rg][r], m);
    if (ln == 0)
        #pragma unroll
        for (int rg = 0; rg < 2; ++rg)
            #pragma unroll
            for (int r = 0; r < 4; ++r)
                atomicAdd(&sums[i0 + rg * 16 + q * 4 + r], p[rg][r]);
}

__global__ void recip_kernel(const float* __restrict__ s, float* __restrict__ r) {
    int i = blockIdx.x * 256 + threadIdx.x;
    r[i] = 1.0f / s[i];
}

// loss = sum_ij -label[i,j] * log( (e*rl_i+eps)*(e*rc_j+eps) ),  e = exp(s-SHIFT)
// TRANSPOSED MFMA (acc = mfma(b, a)): lane = one S-row, 4 consecutive S-cols
// per reg -> label & 1/colsum are float4 loads; 1/rowsum is scalar per rg.
// B-tile (128 cols x 128) staged ONCE per block into LDS with XOR-swizzled
// 16B slots (slot ^= row&7): protects against label-stream cache eviction and
// makes ds_read_b128 conflict-free (unswizzled = 16-way: 16 ln-lanes, 256B row
// stride, same bank).
__global__ __launch_bounds__(256)
void loss_kernel(const __bf16* __restrict__ A, const __bf16* __restrict__ B,
                 const float* __restrict__ lrowR, const float* __restrict__ lcolR,
                 const float* __restrict__ label, float* __restrict__ out) {
    __shared__ alignas(16) __bf16 Bs[128 * 128];   // 32KB swizzled B-tile
    const int tid = threadIdx.x;
    const int w = tid >> 6, lane = tid & 63, q = lane >> 4, ln = lane & 15;
    const int i0 = blockIdx.y * 128 + w * 32;   // 32 rows per wave
    const int jbase = blockIdx.x * 128;         // 128 cols per block

    // stage B rows [jbase, jbase+128): 2048 16B chunks, 8 per thread
    {
        const bf16x8* src = reinterpret_cast<const bf16x8*>(B + (size_t)jbase * MM);
        char* dst = reinterpret_cast<char*>(Bs);
        #pragma unroll
        for (int u = 0; u < 8; ++u) {
            int ch = u * 256 + tid;
            int row = ch >> 4, slot = ch & 15;
            bf16x8 v = src[ch];
            *reinterpret_cast<bf16x8*>(dst + row * 256 + ((slot ^ (row & 7)) << 4)) = v;
        }
    }

    const floatx4 accInit = {-SHIFT, -SHIFT, -SHIFT, -SHIFT};

    bf16x8 a[2][4];
    float rl[2];
    const float* labp[2];
    #pragma unroll
    for (int rg = 0; rg < 2; ++rg) {
        const int row = i0 + rg * 16 + ln;
        LOAD_A(a[rg], A + (size_t)row * MM + q * 8);
        rl[rg] = lrowR[row];
        labp[rg] = label + (size_t)row * NN;
    }
    __syncthreads();

    const char* bsc = reinterpret_cast<const char*>(Bs);
    const int swz = (ln & 7);
    float lacc = 0.f;
    #pragma unroll
    for (int js = 0; js < 2; ++js) {
        const int j0 = jbase + js * 64;
        floatx4 rc[4], lb[2][4];
        #pragma unroll
        for (int cg = 0; cg < 4; ++cg) {
            const int c4 = j0 + cg * 16 + q * 4;
            rc[cg] = *reinterpret_cast<const floatx4*>(&lcolR[c4]);
            lb[0][cg] = *reinterpret_cast<const floatx4*>(&labp[0][c4]);
            lb[1][cg] = *reinterpret_cast<const floatx4*>(&labp[1][c4]);
        }
        #pragma unroll
        for (int cg = 0; cg < 4; ++cg) {
            const int lrow = js * 64 + cg * 16 + ln;    // lrow&7 == ln&7
            const char* bp = bsc + lrow * 256;
            bf16x8 b[4];
            #pragma unroll
            for (int k = 0; k < 4; ++k)
                b[k] = *reinterpret_cast<const bf16x8*>(bp + (((q + 4 * k) ^ swz) << 4));
            floatx4 acc0 = accInit, acc1 = accInit;
            #pragma unroll
            for (int k = 0; k < 4; ++k) {
                acc0 = __builtin_amdgcn_mfma_f32_16x16x32_bf16(b[k], a[0][k], acc0, 0, 0, 0);
                acc1 = __builtin_amdgcn_mfma_f32_16x16x32_bf16(b[k], a[1][k], acc1, 0, 0, 0);
            }
            #pragma unroll
            for (int r = 0; r < 4; ++r) {
                float e0 = __expf(acc0[r]);
                float t0 = __logf(fmaf(e0, rl[0], EPSF) * fmaf(e0, rc[cg][r], EPSF));
                lacc = fmaf(lb[0][cg][r], t0, lacc);
                float e1 = __expf(acc1[r]);
                float t1 = __logf(fmaf(e1, rl[1], EPSF) * fmaf(e1, rc[cg][r], EPSF));
                lacc = fmaf(lb[1][cg][r], t1, lacc);
            }
        }
    }

    #pragma unroll
    for (int m = 1; m <= 32; m <<= 1) lacc += __shfl_xor(lacc, m);
    __shared__ float red[4];
    if (lane == 0) red[w] = lacc;
    __syncthreads();
    if (tid == 0) atomicAdd(out, -((red[0] + red[1]) + (red[2] + red[3])));
}

extern "C" void kernel_launch(void* const* d_in, const int* in_sizes, int n_in,
                              void* d_out, int out_size, void* d_ws, size_t ws_size,
                              hipStream_t stream) {
    const float* out1 = (const float*)d_in[0];
    const float* out2 = (const float*)d_in[1];
    const float* label = (const float*)d_in[2];

    char* ws = (char*)d_ws;
    __bf16* out1b = (__bf16*)ws;                          // 2 MB
    __bf16* out2b = (__bf16*)(ws + (size_t)(2 << 20));    // 2 MB
    float* sums   = (float*)(ws + (size_t)(4 << 20));     // 2*NN floats (64 KB)
    float* recips = sums + 2 * NN;                        // 2*NN floats (64 KB)

    // convert also zeroes sums + d_out (replaces two memset nodes)
    convert_kernel<<<dim3(1024, 2), 256, 0, stream>>>(out1, out2, out1b, out2b,
                                                      sums, (float*)d_out);

    // single S pass -> row sums + col sums; streams label into L3 as prefetch
    sums_kernel<<<dim3(16, 64), 256, 0, stream>>>(out2b, out1b, label, sums);
    recip_kernel<<<dim3(64), 256, 0, stream>>>(sums, recips);

    loss_kernel<<<dim3(64, 64), 256, 0, stream>>>(out2b, out1b,
                                                  recips,          // 1/rowsum
                                                  recips + NN,     // 1/colsum
                                                  label, (float*)d_out);
}

// Round 2
// 438.898 us; speedup vs baseline: 1.0456x; 1.0292x over previous
//
#include <hip/hip_runtime.h>
#include <hip/hip_bf16.h>
#include <stdint.h>

#define NN 8192
#define MM 128
#define EPSF 1e-4f
#define SHIFT 30.0f

typedef __bf16 bf16x8 __attribute__((ext_vector_type(8)));
typedef float floatx4 __attribute__((ext_vector_type(4)));

// Fire-and-forget 16B global->LDS load, used purely as an L3-warming
// prefetch for the TAIL HALF of label (128MB -- fits L3 without
// self-eviction, unlike the full 256MB which equals L3 capacity and
// thrashed in round 1).  Dest is a garbage sink; nobody reads it.
__device__ __forceinline__ void pf16(const float* g, void* lds) {
    __builtin_amdgcn_global_load_lds(
        (__attribute__((address_space(1))) void*)(uintptr_t)g,
        (__attribute__((address_space(3))) void*)(uint32_t)(uintptr_t)lds,
        16, 0, 0);
}

// Convert 8 consecutive fp32 to bf16x8 (RNE cast, identical to the old
// convert_kernel -> bit-identical MFMA inputs).
#define CVT8(dst, ptr)                                                        \
    do {                                                                      \
        float4 v0_ = *reinterpret_cast<const float4*>(ptr);                   \
        float4 v1_ = *reinterpret_cast<const float4*>((ptr) + 4);             \
        bf16x8 t_ = { (__bf16)v0_.x, (__bf16)v0_.y, (__bf16)v0_.z,            \
                      (__bf16)v0_.w, (__bf16)v1_.x, (__bf16)v1_.y,            \
                      (__bf16)v1_.z, (__bf16)v1_.w };                         \
        dst = t_;                                                             \
    } while (0)

// ONE pass over S = A @ B^T (fp32 inputs, inline bf16 convert) producing
// BOTH row sums and col sums of exp(S-SHIFT).
// Key change vs round 1: B js-tile staged ONCE per block into LDS
// (double-buffered, XOR-swizzled) instead of 4x redundant per-wave global
// loads -- cuts 512MB of L1/L2 B-traffic to 128MB + conflict-free LDS reads.
__global__ __launch_bounds__(256)
void sums_kernel(const float* __restrict__ A, const float* __restrict__ B,
                 const float* __restrict__ label, float* __restrict__ sums) {
    __shared__ alignas(16) __bf16 Bs[2][64 * 128];   // 2 x 16KB double buffer
    __shared__ alignas(16) char pfbuf[1024];         // prefetch garbage sink
    const int tid = threadIdx.x;
    const int w = tid >> 6, lane = tid & 63, q = lane >> 4, ln = lane & 15;
    const int i0 = blockIdx.y * 128 + w * 32;   // 32 rows per wave
    const int jbase = blockIdx.x * 512;         // 512 cols per block
    const int bid = blockIdx.y * gridDim.x + blockIdx.x;    // 0..1023
    // tail half of label: 32768 floats (128KB) per block
    const float* pfb = label + (size_t)NN * NN / 2 + (size_t)bid * 32768
                       + w * 1024 + lane * 4;

    const floatx4 accInit = {-SHIFT, -SHIFT, -SHIFT, -SHIFT};

    // A: convert own 32 rows per wave, fp32 -> bf16 in registers
    bf16x8 a[2][4];
    #pragma unroll
    for (int rg = 0; rg < 2; ++rg) {
        const float* ap = A + (size_t)(i0 + rg * 16 + ln) * MM + q * 8;
        #pragma unroll
        for (int k = 0; k < 4; ++k)
            CVT8(a[rg][k], ap + k * 32);
    }

// stage one 64x128 B js-tile (fp32 -> bf16) into LDS, 16B-slot swizzle
#define STAGE(dstbuf, js_)                                                    \
    do {                                                                      \
        const float* srcb_ = B + (size_t)(jbase + (js_) * 64) * MM;           \
        char* d_ = reinterpret_cast<char*>(dstbuf);                           \
        _Pragma("unroll")                                                     \
        for (int u_ = 0; u_ < 4; ++u_) {                                      \
            int ch_ = u_ * 256 + tid;                                         \
            int row_ = ch_ >> 4, slot_ = ch_ & 15;                            \
            bf16x8 t2_;                                                       \
            CVT8(t2_, srcb_ + row_ * MM + slot_ * 8);                         \
            *reinterpret_cast<bf16x8*>(                                       \
                d_ + row_ * 256 + ((slot_ ^ (row_ & 7)) << 4)) = t2_;         \
        }                                                                     \
    } while (0)

    float p[2][4] = {{0.f, 0.f, 0.f, 0.f}, {0.f, 0.f, 0.f, 0.f}};

    STAGE(Bs[0], 0);
    int buf = 0;
    for (int js = 0; js < 8; ++js) {
        __syncthreads();    // staged buf ready; prev reads of buf^1 done
        // issue label prefetch early so its latency hides under this js
        #pragma unroll
        for (int u = 0; u < 4; ++u)
            pf16(pfb + js * 4096 + u * 256, pfbuf);
        if (js < 7) STAGE(Bs[buf ^ 1], js + 1);

        const int j0 = jbase + js * 64;
        const char* bsc = reinterpret_cast<const char*>(Bs[buf]);
        const int sw = ln & 7;
        #pragma unroll
        for (int cg = 0; cg < 4; ++cg) {
            const char* bp = bsc + (cg * 16 + ln) * 256;
            bf16x8 b[4];
            #pragma unroll
            for (int k = 0; k < 4; ++k)
                b[k] = *reinterpret_cast<const bf16x8*>(bp + (((q + 4 * k) ^ sw) << 4));
            floatx4 acc0 = accInit, acc1 = accInit;
            #pragma unroll
            for (int k = 0; k < 4; ++k) {
                acc0 = __builtin_amdgcn_mfma_f32_16x16x32_bf16(a[0][k], b[k], acc0, 0, 0, 0);
                acc1 = __builtin_amdgcn_mfma_f32_16x16x32_bf16(a[1][k], b[k], acc1, 0, 0, 0);
            }
            float e0[4], e1[4];
            #pragma unroll
            for (int r = 0; r < 4; ++r) {
                e0[r] = __expf(acc0[r]);
                e1[r] = __expf(acc1[r]);
                p[0][r] += e0[r];
                p[1][r] += e1[r];
            }
            float c = ((e0[0] + e0[1]) + (e0[2] + e0[3])) +
                      ((e1[0] + e1[1]) + (e1[2] + e1[3]));
            c += __shfl_xor(c, 16);
            c += __shfl_xor(c, 32);
            if (q == 0) atomicAdd(&sums[NN + j0 + cg * 16 + ln], c);
        }
        buf ^= 1;
    }
#undef STAGE

    // row sums: reduce across the 16 ln-lanes of each quad
    #pragma unroll
    for (int m = 1; m <= 8; m <<= 1)
        #pragma unroll
        for (int rg = 0; rg < 2; ++rg)
            #pragma unroll
            for (int r = 0; r < 4; ++r)
                p[rg][r] += __shfl_xor(p[rg][r], m);
    if (ln == 0)
        #pragma unroll
        for (int rg = 0; rg < 2; ++rg)
            #pragma unroll
            for (int r = 0; r < 4; ++r)
                atomicAdd(&sums[i0 + rg * 16 + q * 4 + r], p[rg][r]);
}

// loss = sum_ij -label[i,j] * log( (e*rl_i+eps)*(e*rc_j+eps) ),  e = exp(s-SHIFT)
// TRANSPOSED MFMA (acc = mfma(b, a)): lane = one S-row, 4 consecutive S-cols
// per reg -> label loads are float4.  Reciprocals computed in-block (1 divide
// per thread, same 1.0f/x sequence as the old recip_kernel -> bit-identical);
// fp32 A/B converted inline (replaces convert_kernel).
__global__ __launch_bounds__(256)
void loss_kernel(const float* __restrict__ A, const float* __restrict__ B,
                 const float* __restrict__ sums, const float* __restrict__ label,
                 float* __restrict__ out) {
    __shared__ alignas(16) __bf16 Bs[128 * 128];   // 32KB swizzled B-tile
    __shared__ float Rr[128], Rc[128];
    __shared__ float red[4];
    const int tid = threadIdx.x;
    const int w = tid >> 6, lane = tid & 63, q = lane >> 4, ln = lane & 15;
    const int i0 = blockIdx.y * 128 + w * 32;   // 32 rows per wave
    const int jbase = blockIdx.x * 128;         // 128 cols per block

    // per-block reciprocals of the needed row/col sums (1 divide per thread)
    if (tid < 128) Rr[tid] = 1.0f / sums[blockIdx.y * 128 + tid];
    else           Rc[tid - 128] = 1.0f / sums[NN + jbase + (tid - 128)];

    // stage B rows [jbase, jbase+128) fp32 -> bf16, swizzled 16B slots
    {
        const float* srcb = B + (size_t)jbase * MM;
        char* d = reinterpret_cast<char*>(Bs);
        #pragma unroll
        for (int u = 0; u < 8; ++u) {
            int ch = u * 256 + tid;
            int row = ch >> 4, slot = ch & 15;
            bf16x8 t;
            CVT8(t, srcb + row * MM + slot * 8);
            *reinterpret_cast<bf16x8*>(d + row * 256 + ((slot ^ (row & 7)) << 4)) = t;
        }
    }

    const floatx4 accInit = {-SHIFT, -SHIFT, -SHIFT, -SHIFT};

    bf16x8 a[2][4];
    const float* labp[2];
    #pragma unroll
    for (int rg = 0; rg < 2; ++rg) {
        const int row = i0 + rg * 16 + ln;
        const float* ap = A + (size_t)row * MM + q * 8;
        #pragma unroll
        for (int k = 0; k < 4; ++k)
            CVT8(a[rg][k], ap + k * 32);
        labp[rg] = label + (size_t)row * NN;
    }
    __syncthreads();

    const float rl[2] = { Rr[w * 32 + ln], Rr[w * 32 + 16 + ln] };

    const char* bsc = reinterpret_cast<const char*>(Bs);
    const int sw = ln & 7;
    float lacc = 0.f;
    #pragma unroll
    for (int js = 0; js < 2; ++js) {
        const int j0 = js * 64;
        floatx4 rc[4], lb[2][4];
        #pragma unroll
        for (int cg = 0; cg < 4; ++cg) {
            const int c4 = j0 + cg * 16 + q * 4;
            rc[cg] = *reinterpret_cast<const floatx4*>(&Rc[c4]);
            lb[0][cg] = *reinterpret_cast<const floatx4*>(&labp[0][jbase + c4]);
            lb[1][cg] = *reinterpret_cast<const floatx4*>(&labp[1][jbase + c4]);
        }
        #pragma unroll
        for (int cg = 0; cg < 4; ++cg) {
            const char* bp = bsc + (j0 + cg * 16 + ln) * 256;   // (j0+cg*16)&7==0
            bf16x8 b[4];
            #pragma unroll
            for (int k = 0; k < 4; ++k)
                b[k] = *reinterpret_cast<const bf16x8*>(bp + (((q + 4 * k) ^ sw) << 4));
            floatx4 acc0 = accInit, acc1 = accInit;
            #pragma unroll
            for (int k = 0; k < 4; ++k) {
                acc0 = __builtin_amdgcn_mfma_f32_16x16x32_bf16(b[k], a[0][k], acc0, 0, 0, 0);
                acc1 = __builtin_amdgcn_mfma_f32_16x16x32_bf16(b[k], a[1][k], acc1, 0, 0, 0);
            }
            #pragma unroll
            for (int r = 0; r < 4; ++r) {
                float e0 = __expf(acc0[r]);
                float t0 = __logf(fmaf(e0, rl[0], EPSF) * fmaf(e0, rc[cg][r], EPSF));
                lacc = fmaf(lb[0][cg][r], t0, lacc);
                float e1 = __expf(acc1[r]);
                float t1 = __logf(fmaf(e1, rl[1], EPSF) * fmaf(e1, rc[cg][r], EPSF));
                lacc = fmaf(lb[1][cg][r], t1, lacc);
            }
        }
    }

    #pragma unroll
    for (int m = 1; m <= 32; m <<= 1) lacc += __shfl_xor(lacc, m);
    if (lane == 0) red[w] = lacc;
    __syncthreads();
    if (tid == 0) atomicAdd(out, -((red[0] + red[1]) + (red[2] + red[3])));
}

extern "C" void kernel_launch(void* const* d_in, const int* in_sizes, int n_in,
                              void* d_out, int out_size, void* d_ws, size_t ws_size,
                              hipStream_t stream) {
    const float* out1 = (const float*)d_in[0];
    const float* out2 = (const float*)d_in[1];
    const float* label = (const float*)d_in[2];

    float* sums = (float*)d_ws;                           // 2*NN floats (64 KB)

    hipMemsetAsync(sums, 0, 2 * NN * sizeof(float), stream);
    hipMemsetAsync(d_out, 0, sizeof(float), stream);

    // S = out2 @ out1^T; one pass -> row sums + col sums (+ tail-half label
    // prefetch into L3)
    sums_kernel<<<dim3(16, 64), 256, 0, stream>>>(out2, out1, label, sums);

    // loss pass: inline recip + inline convert; label tail comes from L3
    loss_kernel<<<dim3(64, 64), 256, 0, stream>>>(out2, out1, sums, label,
                                                  (float*)d_out);
}

// Round 3
// 432.562 us; speedup vs baseline: 1.0609x; 1.0146x over previous
//
#include <hip/hip_runtime.h>
#include <hip/hip_bf16.h>
#include <stdint.h>

#define NN 8192
#define MM 128
#define EPSF 1e-4f
#define SHIFT 30.0f

typedef __bf16 bf16x8 __attribute__((ext_vector_type(8)));
typedef float floatx4 __attribute__((ext_vector_type(4)));

// Fire-and-forget 16B global->LDS load: L3-warming prefetch for the HEAD
// half of label (head is consumed FIRST by loss_kernel -> zero eviction
// window, unlike round 2's tail-prefetch).  Dest is a garbage sink.
__device__ __forceinline__ void pf16(const float* g, void* lds) {
    __builtin_amdgcn_global_load_lds(
        (__attribute__((address_space(1))) void*)(uintptr_t)g,
        (__attribute__((address_space(3))) void*)(uint32_t)(uintptr_t)lds,
        16, 0, 0);
}

// Convert 8 consecutive fp32 to bf16x8 (RNE cast -> bit-identical MFMA inputs).
#define CVT8(dst, ptr)                                                        \
    do {                                                                      \
        float4 v0_ = *reinterpret_cast<const float4*>(ptr);                   \
        float4 v1_ = *reinterpret_cast<const float4*>((ptr) + 4);             \
        bf16x8 t_ = { (__bf16)v0_.x, (__bf16)v0_.y, (__bf16)v0_.z,            \
                      (__bf16)v0_.w, (__bf16)v1_.x, (__bf16)v1_.y,            \
                      (__bf16)v1_.z, (__bf16)v1_.w };                         \
        dst = t_;                                                             \
    } while (0)

// ONE pass over S = A @ B^T (fp32 inputs, inline bf16 convert) producing
// BOTH row sums and col sums of exp(S-SHIFT).
// Round-3 geometry: 64 rows per WAVE (4 row-groups), 256x256 per block,
// grid 32x32 -> MFMA:ds_read ratio 4:1 (was 2:1), half the staging traffic
// and barriers per output, still 4 blocks/CU (32KB LDS).
__global__ __launch_bounds__(256)
void sums_kernel(const float* __restrict__ A, const float* __restrict__ B,
                 const float* __restrict__ label, float* __restrict__ sums,
                 float* __restrict__ out) {
    __shared__ alignas(16) __bf16 Bs[2][64 * 128];   // 2 x 16KB double buffer
    __shared__ alignas(16) char pfbuf[1024];         // prefetch garbage sink
    const int tid = threadIdx.x;
    const int w = tid >> 6, lane = tid & 63, q = lane >> 4, ln = lane & 15;
    const int i0 = blockIdx.y * 256 + w * 64;   // 64 rows per wave
    const int jbase = blockIdx.x * 256;         // 256 cols per block
    const int bid = blockIdx.y * gridDim.x + blockIdx.x;    // 0..1023
    // head half of label: 32768 floats (128KB) per block
    const float* pfb = label + (size_t)bid * 32768 + w * 8192 + lane * 4;

    if (bid == 0 && tid == 0) *out = 0.f;   // replaces d_out memset node

    const floatx4 accInit = {-SHIFT, -SHIFT, -SHIFT, -SHIFT};

    // A: convert own 64 rows per wave, fp32 -> bf16 in registers
    bf16x8 a[4][4];
    #pragma unroll
    for (int rg = 0; rg < 4; ++rg) {
        const float* ap = A + (size_t)(i0 + rg * 16 + ln) * MM + q * 8;
        #pragma unroll
        for (int k = 0; k < 4; ++k)
            CVT8(a[rg][k], ap + k * 32);
    }

// stage one 64x128 B js-tile (fp32 -> bf16) into LDS, 16B-slot swizzle
#define STAGE(dstbuf, js_)                                                    \
    do {                                                                      \
        const float* srcb_ = B + (size_t)(jbase + (js_) * 64) * MM;           \
        char* d_ = reinterpret_cast<char*>(dstbuf);                           \
        _Pragma("unroll")                                                     \
        for (int u_ = 0; u_ < 4; ++u_) {                                      \
            int ch_ = u_ * 256 + tid;                                         \
            int row_ = ch_ >> 4, slot_ = ch_ & 15;                            \
            bf16x8 t2_;                                                       \
            CVT8(t2_, srcb_ + row_ * MM + slot_ * 8);                         \
            *reinterpret_cast<bf16x8*>(                                       \
                d_ + row_ * 256 + ((slot_ ^ (row_ & 7)) << 4)) = t2_;         \
        }                                                                     \
    } while (0)

    float p[4][4];
    #pragma unroll
    for (int rg = 0; rg < 4; ++rg)
        #pragma unroll
        for (int r = 0; r < 4; ++r) p[rg][r] = 0.f;

    STAGE(Bs[0], 0);
    int buf = 0;
    for (int js = 0; js < 4; ++js) {
        __syncthreads();    // staged buf ready; prev reads of buf^1 done
        if (js < 3) STAGE(Bs[buf ^ 1], js + 1);
        // prefetch AFTER stage loads: youngest in vmcnt queue, so the
        // compiler's wait for staged data does not drain the prefetches
        #pragma unroll
        for (int u = 0; u < 8; ++u)
            pf16(pfb + js * 2048 + u * 256, pfbuf);

        const int j0 = jbase + js * 64;
        const char* bsc = reinterpret_cast<const char*>(Bs[buf]);
        const int sw = ln & 7;
        #pragma unroll
        for (int cg = 0; cg < 4; ++cg) {
            const char* bp = bsc + (cg * 16 + ln) * 256;
            bf16x8 b[4];
            #pragma unroll
            for (int k = 0; k < 4; ++k)
                b[k] = *reinterpret_cast<const bf16x8*>(bp + (((q + 4 * k) ^ sw) << 4));
            floatx4 acc[4] = {accInit, accInit, accInit, accInit};
            #pragma unroll
            for (int k = 0; k < 4; ++k)
                #pragma unroll
                for (int rg = 0; rg < 4; ++rg)
                    acc[rg] = __builtin_amdgcn_mfma_f32_16x16x32_bf16(a[rg][k], b[k], acc[rg], 0, 0, 0);
            float c = 0.f;
            #pragma unroll
            for (int rg = 0; rg < 4; ++rg) {
                float e[4];
                #pragma unroll
                for (int r = 0; r < 4; ++r) {
                    e[r] = __expf(acc[rg][r]);
                    p[rg][r] += e[r];
                }
                c += (e[0] + e[1]) + (e[2] + e[3]);
            }
            c += __shfl_xor(c, 16);
            c += __shfl_xor(c, 32);
            if (q == 0) atomicAdd(&sums[NN + j0 + cg * 16 + ln], c);
        }
        buf ^= 1;
    }
#undef STAGE

    // row sums: reduce across the 16 ln-lanes of each quad
    #pragma unroll
    for (int m = 1; m <= 8; m <<= 1)
        #pragma unroll
        for (int rg = 0; rg < 4; ++rg)
            #pragma unroll
            for (int r = 0; r < 4; ++r)
                p[rg][r] += __shfl_xor(p[rg][r], m);
    if (ln == 0)
        #pragma unroll
        for (int rg = 0; rg < 4; ++rg)
            #pragma unroll
            for (int r = 0; r < 4; ++r)
                atomicAdd(&sums[i0 + rg * 16 + q * 4 + r], p[rg][r]);
}

// loss = sum_ij -label[i,j] * log( (e*rl_i+eps)*(e*rc_j+eps) ),  e = exp(s-SHIFT)
// TRANSPOSED MFMA (acc = mfma(b, a)): lane = one S-row, 4 consecutive S-cols
// per reg -> label loads are float4.  Reciprocals computed in-block (1 divide
// per thread, bit-identical to the old recip_kernel); fp32 A/B converted
// inline.  Head half of label comes from L3 (warmed by sums_kernel).
__global__ __launch_bounds__(256)
void loss_kernel(const float* __restrict__ A, const float* __restrict__ B,
                 const float* __restrict__ sums, const float* __restrict__ label,
                 float* __restrict__ out) {
    __shared__ alignas(16) __bf16 Bs[128 * 128];   // 32KB swizzled B-tile
    __shared__ float Rr[128], Rc[128];
    __shared__ float red[4];
    const int tid = threadIdx.x;
    const int w = tid >> 6, lane = tid & 63, q = lane >> 4, ln = lane & 15;
    const int i0 = blockIdx.y * 128 + w * 32;   // 32 rows per wave
    const int jbase = blockIdx.x * 128;         // 128 cols per block

    // per-block reciprocals of the needed row/col sums (1 divide per thread)
    if (tid < 128) Rr[tid] = 1.0f / sums[blockIdx.y * 128 + tid];
    else           Rc[tid - 128] = 1.0f / sums[NN + jbase + (tid - 128)];

    // stage B rows [jbase, jbase+128) fp32 -> bf16, swizzled 16B slots
    {
        const float* srcb = B + (size_t)jbase * MM;
        char* d = reinterpret_cast<char*>(Bs);
        #pragma unroll
        for (int u = 0; u < 8; ++u) {
            int ch = u * 256 + tid;
            int row = ch >> 4, slot = ch & 15;
            bf16x8 t;
            CVT8(t, srcb + row * MM + slot * 8);
            *reinterpret_cast<bf16x8*>(d + row * 256 + ((slot ^ (row & 7)) << 4)) = t;
        }
    }

    const floatx4 accInit = {-SHIFT, -SHIFT, -SHIFT, -SHIFT};

    bf16x8 a[2][4];
    const float* labp[2];
    #pragma unroll
    for (int rg = 0; rg < 2; ++rg) {
        const int row = i0 + rg * 16 + ln;
        const float* ap = A + (size_t)row * MM + q * 8;
        #pragma unroll
        for (int k = 0; k < 4; ++k)
            CVT8(a[rg][k], ap + k * 32);
        labp[rg] = label + (size_t)row * NN;
    }
    __syncthreads();

    const float rl[2] = { Rr[w * 32 + ln], Rr[w * 32 + 16 + ln] };

    const char* bsc = reinterpret_cast<const char*>(Bs);
    const int sw = ln & 7;
    float lacc = 0.f;
    #pragma unroll
    for (int js = 0; js < 2; ++js) {
        const int j0 = js * 64;
        floatx4 rc[4], lb[2][4];
        #pragma unroll
        for (int cg = 0; cg < 4; ++cg) {
            const int c4 = j0 + cg * 16 + q * 4;
            rc[cg] = *reinterpret_cast<const floatx4*>(&Rc[c4]);
            lb[0][cg] = *reinterpret_cast<const floatx4*>(&labp[0][jbase + c4]);
            lb[1][cg] = *reinterpret_cast<const floatx4*>(&labp[1][jbase + c4]);
        }
        #pragma unroll
        for (int cg = 0; cg < 4; ++cg) {
            const char* bp = bsc + (j0 + cg * 16 + ln) * 256;   // (j0+cg*16)&7==0
            bf16x8 b[4];
            #pragma unroll
            for (int k = 0; k < 4; ++k)
                b[k] = *reinterpret_cast<const bf16x8*>(bp + (((q + 4 * k) ^ sw) << 4));
            floatx4 acc0 = accInit, acc1 = accInit;
            #pragma unroll
            for (int k = 0; k < 4; ++k) {
                acc0 = __builtin_amdgcn_mfma_f32_16x16x32_bf16(b[k], a[0][k], acc0, 0, 0, 0);
                acc1 = __builtin_amdgcn_mfma_f32_16x16x32_bf16(b[k], a[1][k], acc1, 0, 0, 0);
            }
            #pragma unroll
            for (int r = 0; r < 4; ++r) {
                float e0 = __expf(acc0[r]);
                float t0 = __logf(fmaf(e0, rl[0], EPSF) * fmaf(e0, rc[cg][r], EPSF));
                lacc = fmaf(lb[0][cg][r], t0, lacc);
                float e1 = __expf(acc1[r]);
                float t1 = __logf(fmaf(e1, rl[1], EPSF) * fmaf(e1, rc[cg][r], EPSF));
                lacc = fmaf(lb[1][cg][r], t1, lacc);
            }
        }
    }

    #pragma unroll
    for (int m = 1; m <= 32; m <<= 1) lacc += __shfl_xor(lacc, m);
    if (lane == 0) red[w] = lacc;
    __syncthreads();
    if (tid == 0) atomicAdd(out, -((red[0] + red[1]) + (red[2] + red[3])));
}

extern "C" void kernel_launch(void* const* d_in, const int* in_sizes, int n_in,
                              void* d_out, int out_size, void* d_ws, size_t ws_size,
                              hipStream_t stream) {
    const float* out1 = (const float*)d_in[0];
    const float* out2 = (const float*)d_in[1];
    const float* label = (const float*)d_in[2];

    float* sums = (float*)d_ws;                           // 2*NN floats (64 KB)

    hipMemsetAsync(sums, 0, 2 * NN * sizeof(float), stream);

    // S = out2 @ out1^T; one pass -> row sums + col sums (+ head-half label
    // prefetch into L3); also zeroes d_out
    sums_kernel<<<dim3(32, 32), 256, 0, stream>>>(out2, out1, label, sums,
                                                  (float*)d_out);

    // loss pass: inline recip + inline convert; label head comes from L3
    loss_kernel<<<dim3(64, 64), 256, 0, stream>>>(out2, out1, sums, label,
                                                  (float*)d_out);
}

// Round 5
// 422.404 us; speedup vs baseline: 1.0864x; 1.0240x over previous
//
#include <hip/hip_runtime.h>
#include <hip/hip_bf16.h>
#include <stdint.h>

#define NN 8192
#define MM 128
#define EPSF 1e-4f
#define SHIFT 30.0f

typedef __bf16 bf16x8 __attribute__((ext_vector_type(8)));
typedef float floatx4 __attribute__((ext_vector_type(4)));

// Fire-and-forget 16B global->LDS load: L3-warming prefetch for the HEAD
// half of label (head is consumed FIRST by loss_kernel -> zero eviction
// window).  Dest is a garbage sink.
__device__ __forceinline__ void pf16(const float* g, void* lds) {
    __builtin_amdgcn_global_load_lds(
        (__attribute__((address_space(1))) void*)(uintptr_t)g,
        (__attribute__((address_space(3))) void*)(uint32_t)(uintptr_t)lds,
        16, 0, 0);
}

// Convert 8 consecutive fp32 to bf16x8 (RNE cast -> bit-identical MFMA inputs).
#define CVT8(dst, ptr)                                                        \
    do {                                                                      \
        float4 v0_ = *reinterpret_cast<const float4*>(ptr);                   \
        float4 v1_ = *reinterpret_cast<const float4*>((ptr) + 4);             \
        bf16x8 t_ = { (__bf16)v0_.x, (__bf16)v0_.y, (__bf16)v0_.z,            \
                      (__bf16)v0_.w, (__bf16)v1_.x, (__bf16)v1_.y,            \
                      (__bf16)v1_.z, (__bf16)v1_.w };                         \
        dst = t_;                                                             \
    } while (0)

// ONE pass over S = A @ B^T (fp32 inputs, inline bf16 convert) producing
// BOTH row sums and col sums of exp(S-SHIFT).  64 rows per wave, 256x256
// per block, grid 32x32; B js-tile double-buffered in swizzled LDS.
// Also prefetches the head half of label into L3 (model-optimal ~128MB:
// any volume in ~76-160MB makes both kernels BW-covered; beyond that it
// just moves serial BW time from loss into sums).
__global__ __launch_bounds__(256)
void sums_kernel(const float* __restrict__ A, const float* __restrict__ B,
                 const float* __restrict__ label, float* __restrict__ sums,
                 float* __restrict__ out) {
    __shared__ alignas(16) __bf16 Bs[2][64 * 128];   // 2 x 16KB double buffer
    __shared__ alignas(16) char pfbuf[1024];         // prefetch garbage sink
    const int tid = threadIdx.x;
    const int w = tid >> 6, lane = tid & 63, q = lane >> 4, ln = lane & 15;
    const int i0 = blockIdx.y * 256 + w * 64;   // 64 rows per wave
    const int jbase = blockIdx.x * 256;         // 256 cols per block
    const int bid = blockIdx.y * gridDim.x + blockIdx.x;    // 0..1023
    // head half of label: 32768 floats (128KB) per block
    const float* pfb = label + (size_t)bid * 32768 + w * 8192 + lane * 4;

    if (bid == 0 && tid == 0) *out = 0.f;   // replaces d_out memset node

    const floatx4 accInit = {-SHIFT, -SHIFT, -SHIFT, -SHIFT};

    // A: convert own 64 rows per wave, fp32 -> bf16 in registers
    bf16x8 a[4][4];
    #pragma unroll
    for (int rg = 0; rg < 4; ++rg) {
        const float* ap = A + (size_t)(i0 + rg * 16 + ln) * MM + q * 8;
        #pragma unroll
        for (int k = 0; k < 4; ++k)
            CVT8(a[rg][k], ap + k * 32);
    }

// stage one 64x128 B js-tile (fp32 -> bf16) into LDS, 16B-slot swizzle
#define STAGE(dstbuf, js_)                                                    \
    do {                                                                      \
        const float* srcb_ = B + (size_t)(jbase + (js_) * 64) * MM;           \
        char* d_ = reinterpret_cast<char*>(dstbuf);                           \
        _Pragma("unroll")                                                     \
        for (int u_ = 0; u_ < 4; ++u_) {                                      \
            int ch_ = u_ * 256 + tid;                                         \
            int row_ = ch_ >> 4, slot_ = ch_ & 15;                            \
            bf16x8 t2_;                                                       \
            CVT8(t2_, srcb_ + row_ * MM + slot_ * 8);                         \
            *reinterpret_cast<bf16x8*>(                                       \
                d_ + row_ * 256 + ((slot_ ^ (row_ & 7)) << 4)) = t2_;         \
        }                                                                     \
    } while (0)

    float p[4][4];
    #pragma unroll
    for (int rg = 0; rg < 4; ++rg)
        #pragma unroll
        for (int r = 0; r < 4; ++r) p[rg][r] = 0.f;

    STAGE(Bs[0], 0);
    int buf = 0;
    for (int js = 0; js < 4; ++js) {
        __syncthreads();    // staged buf ready; prev reads of buf^1 done
        if (js < 3) STAGE(Bs[buf ^ 1], js + 1);
        // prefetch AFTER stage loads: youngest in vmcnt queue, so the
        // compiler's wait for staged data does not drain the prefetches
        #pragma unroll
        for (int u = 0; u < 8; ++u)
            pf16(pfb + js * 2048 + u * 256, pfbuf);

        const int j0 = jbase + js * 64;
        const char* bsc = reinterpret_cast<const char*>(Bs[buf]);
        const int sw = ln & 7;
        #pragma unroll
        for (int cg = 0; cg < 4; ++cg) {
            const char* bp = bsc + (cg * 16 + ln) * 256;
            bf16x8 b[4];
            #pragma unroll
            for (int k = 0; k < 4; ++k)
                b[k] = *reinterpret_cast<const bf16x8*>(bp + (((q + 4 * k) ^ sw) << 4));
            floatx4 acc[4] = {accInit, accInit, accInit, accInit};
            #pragma unroll
            for (int k = 0; k < 4; ++k)
                #pragma unroll
                for (int rg = 0; rg < 4; ++rg)
                    acc[rg] = __builtin_amdgcn_mfma_f32_16x16x32_bf16(a[rg][k], b[k], acc[rg], 0, 0, 0);
            float c = 0.f;
            #pragma unroll
            for (int rg = 0; rg < 4; ++rg) {
                float e[4];
                #pragma unroll
                for (int r = 0; r < 4; ++r) {
                    e[r] = __expf(acc[rg][r]);
                    p[rg][r] += e[r];
                }
                c += (e[0] + e[1]) + (e[2] + e[3]);
            }
            c += __shfl_xor(c, 16);
            c += __shfl_xor(c, 32);
            if (q == 0) atomicAdd(&sums[NN + j0 + cg * 16 + ln], c);
        }
        buf ^= 1;
    }
#undef STAGE

    // row sums: reduce across the 16 ln-lanes of each quad
    #pragma unroll
    for (int m = 1; m <= 8; m <<= 1)
        #pragma unroll
        for (int rg = 0; rg < 4; ++rg)
            #pragma unroll
            for (int r = 0; r < 4; ++r)
                p[rg][r] += __shfl_xor(p[rg][r], m);
    if (ln == 0)
        #pragma unroll
        for (int rg = 0; rg < 4; ++rg)
            #pragma unroll
            for (int r = 0; r < 4; ++r)
                atomicAdd(&sums[i0 + rg * 16 + q * 4 + r], p[rg][r]);
}

// loss = sum_ij -label[i,j] * log( (e*rl_i+eps)*(e*rc_j+eps) ),  e = exp(s-SHIFT)
// TRANSPOSED MFMA (acc = mfma(b, a)): lane = one S-row, 4 consecutive S-cols
// per reg -> label loads are float4.
// Round-4 change: ALL 16 label float4 loads per thread are issued at kernel
// start, BEFORE B staging / a-loads / __syncthreads.  Label depends on
// nothing, so its ~900cyc HBM latency hides under the staging phase and the
// compute loop runs with zero label stalls (Little's law: a CU needs ~9KB
// label in flight to sustain its HBM share; interleaved 8-at-a-time issue
// did not get there).  Costs ~+48 VGPR (3 waves/SIMD instead of 4) --
// trading 25% occupancy for 2x per-wave memory-level parallelism.
__global__ __launch_bounds__(256)
void loss_kernel(const float* __restrict__ A, const float* __restrict__ B,
                 const float* __restrict__ sums, const float* __restrict__ label,
                 float* __restrict__ out) {
    __shared__ alignas(16) __bf16 Bs[128 * 128];   // 32KB swizzled B-tile
    __shared__ float Rr[128], Rc[128];
    __shared__ float red[4];
    const int tid = threadIdx.x;
    const int w = tid >> 6, lane = tid & 63, q = lane >> 4, ln = lane & 15;
    const int i0 = blockIdx.y * 128 + w * 32;   // 32 rows per wave
    const int jbase = blockIdx.x * 128;         // 128 cols per block

    // ---- issue ALL label loads first (16 float4 per thread, no deps) ----
    const float* labp[2] = {
        label + (size_t)(i0 + ln) * NN + jbase,
        label + (size_t)(i0 + 16 + ln) * NN + jbase
    };
    floatx4 lb[2][2][4];   // [js][rg][cg]
    #pragma unroll
    for (int js = 0; js < 2; ++js)
        #pragma unroll
        for (int cg = 0; cg < 4; ++cg) {
            const int c4 = js * 64 + cg * 16 + q * 4;
            lb[js][0][cg] = *reinterpret_cast<const floatx4*>(&labp[0][c4]);
            lb[js][1][cg] = *reinterpret_cast<const floatx4*>(&labp[1][c4]);
        }

    // per-block reciprocals of the needed row/col sums (1 divide per thread)
    if (tid < 128) Rr[tid] = 1.0f / sums[blockIdx.y * 128 + tid];
    else           Rc[tid - 128] = 1.0f / sums[NN + jbase + (tid - 128)];

    // stage B rows [jbase, jbase+128) fp32 -> bf16, swizzled 16B slots
    {
        const float* srcb = B + (size_t)jbase * MM;
        char* d = reinterpret_cast<char*>(Bs);
        #pragma unroll
        for (int u = 0; u < 8; ++u) {
            int ch = u * 256 + tid;
            int row = ch >> 4, slot = ch & 15;
            bf16x8 t;
            CVT8(t, srcb + row * MM + slot * 8);
            *reinterpret_cast<bf16x8*>(d + row * 256 + ((slot ^ (row & 7)) << 4)) = t;
        }
    }

    const floatx4 accInit = {-SHIFT, -SHIFT, -SHIFT, -SHIFT};

    bf16x8 a[2][4];
    #pragma unroll
    for (int rg = 0; rg < 2; ++rg) {
        const float* ap = A + (size_t)(i0 + rg * 16 + ln) * MM + q * 8;
        #pragma unroll
        for (int k = 0; k < 4; ++k)
            CVT8(a[rg][k], ap + k * 32);
    }
    __syncthreads();

    const float rl[2] = { Rr[w * 32 + ln], Rr[w * 32 + 16 + ln] };

    const char* bsc = reinterpret_cast<const char*>(Bs);
    const int sw = ln & 7;
    float lacc = 0.f;
    #pragma unroll
    for (int js = 0; js < 2; ++js) {
        const int j0 = js * 64;
        #pragma unroll
        for (int cg = 0; cg < 4; ++cg) {
            // rc broadcast from LDS (same addr within q-group -> conflict-free)
            const floatx4 rc = *reinterpret_cast<const floatx4*>(&Rc[j0 + cg * 16 + q * 4]);
            const char* bp = bsc + (j0 + cg * 16 + ln) * 256;   // (j0+cg*16)&7==0
            bf16x8 b[4];
            #pragma unroll
            for (int k = 0; k < 4; ++k)
                b[k] = *reinterpret_cast<const bf16x8*>(bp + (((q + 4 * k) ^ sw) << 4));
            floatx4 acc0 = accInit, acc1 = accInit;
            #pragma unroll
            for (int k = 0; k < 4; ++k) {
                acc0 = __builtin_amdgcn_mfma_f32_16x16x32_bf16(b[k], a[0][k], acc0, 0, 0, 0);
                acc1 = __builtin_amdgcn_mfma_f32_16x16x32_bf16(b[k], a[1][k], acc1, 0, 0, 0);
            }
            #pragma unroll
            for (int r = 0; r < 4; ++r) {
                float e0 = __expf(acc0[r]);
                float t0 = __logf(fmaf(e0, rl[0], EPSF) * fmaf(e0, rc[r], EPSF));
                lacc = fmaf(lb[js][0][cg][r], t0, lacc);
                float e1 = __expf(acc1[r]);
                float t1 = __logf(fmaf(e1, rl[1], EPSF) * fmaf(e1, rc[r], EPSF));
                lacc = fmaf(lb[js][1][cg][r], t1, lacc);
            }
        }
    }

    #pragma unroll
    for (int m = 1; m <= 32; m <<= 1) lacc += __shfl_xor(lacc, m);
    if (lane == 0) red[w] = lacc;
    __syncthreads();
    if (tid == 0) atomicAdd(out, -((red[0] + red[1]) + (red[2] + red[3])));
}

extern "C" void kernel_launch(void* const* d_in, const int* in_sizes, int n_in,
                              void* d_out, int out_size, void* d_ws, size_t ws_size,
                              hipStream_t stream) {
    const float* out1 = (const float*)d_in[0];
    const float* out2 = (const float*)d_in[1];
    const float* label = (const float*)d_in[2];

    float* sums = (float*)d_ws;                           // 2*NN floats (64 KB)

    hipMemsetAsync(sums, 0, 2 * NN * sizeof(float), stream);

    // S = out2 @ out1^T; one pass -> row sums + col sums (+ head-half label
    // prefetch into L3); also zeroes d_out
    sums_kernel<<<dim3(32, 32), 256, 0, stream>>>(out2, out1, label, sums,
                                                  (float*)d_out);

    // loss pass: all label loads issued up-front, B via swizzled LDS
    loss_kernel<<<dim3(64, 64), 256, 0, stream>>>(out2, out1, sums, label,
                                                  (float*)d_out);
}

// Round 7
// 421.631 us; speedup vs baseline: 1.0884x; 1.0018x over previous
//
#include <hip/hip_runtime.h>
#include <hip/hip_bf16.h>
#include <stdint.h>

#define NN 8192
#define MM 128
#define EPSF 1e-4f
#define SHIFT 30.0f

typedef __bf16 bf16x8 __attribute__((ext_vector_type(8)));
typedef float floatx4 __attribute__((ext_vector_type(4)));

// Fire-and-forget 16B global->LDS load: L3-warming prefetch for the EVEN
// 128-row bands of label (128MB).  Interleaved -- not head/tail -- so that
// during loss_kernel the even-by blocks read L3 while odd-by blocks read
// HBM CONCURRENTLY (label needs >HBM-alone effective BW over loss's
// lifetime; head/tail phasing serialized the two sources).
__device__ __forceinline__ void pf16(const float* g, void* lds) {
    __builtin_amdgcn_global_load_lds(
        (__attribute__((address_space(1))) void*)(uintptr_t)g,
        (__attribute__((address_space(3))) void*)(uint32_t)(uintptr_t)lds,
        16, 0, 0);
}

// Convert 8 consecutive fp32 to bf16x8 (RNE cast -> bit-identical MFMA inputs).
#define CVT8(dst, ptr)                                                        \
    do {                                                                      \
        float4 v0_ = *reinterpret_cast<const float4*>(ptr);                   \
        float4 v1_ = *reinterpret_cast<const float4*>((ptr) + 4);             \
        bf16x8 t_ = { (__bf16)v0_.x, (__bf16)v0_.y, (__bf16)v0_.z,            \
                      (__bf16)v0_.w, (__bf16)v1_.x, (__bf16)v1_.y,            \
                      (__bf16)v1_.z, (__bf16)v1_.w };                         \
        dst = t_;                                                             \
    } while (0)

// ONE pass over S = A @ B^T (fp32 inputs, inline bf16 convert) producing
// BOTH row and col partials of exp(S-SHIFT).  64 rows per wave, 256x256 per
// block, grid 32x32; B js-tile double-buffered in swizzled LDS.
// Round-6: NO atomics, NO memset -- row partials are plain stores
// rowp[bx][i] (complete over the block's 256 cols); col partials combine
// the 4 waves through LDS then store colp[by][j].  loss_kernel sums the 32
// partials per row/col.  Removes the memset graph node + 262K contended
// global atomics, and makes sums output deterministic.
__global__ __launch_bounds__(256)
void sums_kernel(const float* __restrict__ A, const float* __restrict__ B,
                 const float* __restrict__ label,
                 float* __restrict__ rowp, float* __restrict__ colp,
                 float* __restrict__ out) {
    __shared__ alignas(16) __bf16 Bs[2][64 * 128];   // 2 x 16KB double buffer
    __shared__ float colw[4][256];                   // per-wave col partials
    __shared__ alignas(16) char pfbuf[1024];         // prefetch garbage sink
    const int tid = threadIdx.x;
    const int w = tid >> 6, lane = tid & 63, q = lane >> 4, ln = lane & 15;
    const int i0 = blockIdx.y * 256 + w * 64;   // 64 rows per wave
    const int jbase = blockIdx.x * 256;         // 256 cols per block
    const int bid = blockIdx.y * gridDim.x + blockIdx.x;    // 0..1023
    // even 128-row bands of label: band b covers rows [b*256, b*256+128)
    const int band = bid >> 5, sub = bid & 31;   // 32 blocks per band
    const float* pfb = label + (size_t)(band * 256 + sub * 4) * NN
                       + (size_t)w * NN + lane * 4;   // 1 row per wave

    if (bid == 0 && tid == 0) *out = 0.f;   // d_out zero (loss runs after)

    const floatx4 accInit = {-SHIFT, -SHIFT, -SHIFT, -SHIFT};

    // A: convert own 64 rows per wave, fp32 -> bf16 in registers
    bf16x8 a[4][4];
    #pragma unroll
    for (int rg = 0; rg < 4; ++rg) {
        const float* ap = A + (size_t)(i0 + rg * 16 + ln) * MM + q * 8;
        #pragma unroll
        for (int k = 0; k < 4; ++k)
            CVT8(a[rg][k], ap + k * 32);
    }

// stage one 64x128 B js-tile (fp32 -> bf16) into LDS, 16B-slot swizzle
#define STAGE(dstbuf, js_)                                                    \
    do {                                                                      \
        const float* srcb_ = B + (size_t)(jbase + (js_) * 64) * MM;           \
        char* d_ = reinterpret_cast<char*>(dstbuf);                           \
        _Pragma("unroll")                                                     \
        for (int u_ = 0; u_ < 4; ++u_) {                                      \
            int ch_ = u_ * 256 + tid;                                         \
            int row_ = ch_ >> 4, slot_ = ch_ & 15;                            \
            bf16x8 t2_;                                                       \
            CVT8(t2_, srcb_ + row_ * MM + slot_ * 8);                         \
            *reinterpret_cast<bf16x8*>(                                       \
                d_ + row_ * 256 + ((slot_ ^ (row_ & 7)) << 4)) = t2_;         \
        }                                                                     \
    } while (0)

    float p[4][4];
    #pragma unroll
    for (int rg = 0; rg < 4; ++rg)
        #pragma unroll
        for (int r = 0; r < 4; ++r) p[rg][r] = 0.f;

    STAGE(Bs[0], 0);
    int buf = 0;
    for (int js = 0; js < 4; ++js) {
        __syncthreads();    // staged buf ready; prev reads of buf^1 done
        if (js < 3) STAGE(Bs[buf ^ 1], js + 1);
        // prefetch AFTER stage loads: youngest in vmcnt queue, so the
        // compiler's wait for staged data does not drain the prefetches
        #pragma unroll
        for (int u = 0; u < 8; ++u)
            pf16(pfb + js * 2048 + u * 256, pfbuf);

        const char* bsc = reinterpret_cast<const char*>(Bs[buf]);
        const int sw = ln & 7;
        #pragma unroll
        for (int cg = 0; cg < 4; ++cg) {
            const char* bp = bsc + (cg * 16 + ln) * 256;
            bf16x8 b[4];
            #pragma unroll
            for (int k = 0; k < 4; ++k)
                b[k] = *reinterpret_cast<const bf16x8*>(bp + (((q + 4 * k) ^ sw) << 4));
            floatx4 acc[4] = {accInit, accInit, accInit, accInit};
            #pragma unroll
            for (int k = 0; k < 4; ++k)
                #pragma unroll
                for (int rg = 0; rg < 4; ++rg)
                    acc[rg] = __builtin_amdgcn_mfma_f32_16x16x32_bf16(a[rg][k], b[k], acc[rg], 0, 0, 0);
            float c = 0.f;
            #pragma unroll
            for (int rg = 0; rg < 4; ++rg) {
                float e[4];
                #pragma unroll
                for (int r = 0; r < 4; ++r) {
                    e[r] = __expf(acc[rg][r]);
                    p[rg][r] += e[r];
                }
                c += (e[0] + e[1]) + (e[2] + e[3]);
            }
            c += __shfl_xor(c, 16);
            c += __shfl_xor(c, 32);
            // per-wave 64-row col partial -> own LDS slot (no atomic)
            if (q == 0) colw[w][js * 64 + cg * 16 + ln] = c;
        }
        buf ^= 1;
    }
#undef STAGE

    // row partials: reduce across the 16 ln-lanes, plain store (no atomic)
    #pragma unroll
    for (int m = 1; m <= 8; m <<= 1)
        #pragma unroll
        for (int rg = 0; rg < 4; ++rg)
            #pragma unroll
            for (int r = 0; r < 4; ++r)
                p[rg][r] += __shfl_xor(p[rg][r], m);
    if (ln == 0)
        #pragma unroll
        for (int rg = 0; rg < 4; ++rg)
            #pragma unroll
            for (int r = 0; r < 4; ++r)
                rowp[(size_t)blockIdx.x * NN + i0 + rg * 16 + q * 4 + r] = p[rg][r];

    // col partials: combine 4 waves, plain store
    __syncthreads();
    {
        float cs = (colw[0][tid] + colw[1][tid]) + (colw[2][tid] + colw[3][tid]);
        colp[(size_t)blockIdx.y * NN + jbase + tid] = cs;
    }
}

// loss = sum_ij -label[i,j] * log( (e*rl_i+eps)*(e*rc_j+eps) ),  e = exp(s-SHIFT)
// TRANSPOSED MFMA (acc = mfma(b, a)): lane = one S-row, 4 consecutive S-cols
// per reg -> label loads are float4.  All 16 label float4 loads issued at
// kernel start (round-5 win: latency hides under staging/recips/barrier).
// Recips now sum 32 partials per row/col (replaces atomic-built sums).
// Even-by blocks read L3-warm label, odd-by read HBM -- concurrently.
__global__ __launch_bounds__(256)
void loss_kernel(const float* __restrict__ A, const float* __restrict__ B,
                 const float* __restrict__ rowp, const float* __restrict__ colp,
                 const float* __restrict__ label, float* __restrict__ out) {
    __shared__ alignas(16) __bf16 Bs[128 * 128];   // 32KB swizzled B-tile
    __shared__ float Rr[128], Rc[128];
    __shared__ float red[4];
    const int tid = threadIdx.x;
    const int w = tid >> 6, lane = tid & 63, q = lane >> 4, ln = lane & 15;
    const int i0 = blockIdx.y * 128 + w * 32;   // 32 rows per wave
    const int jbase = blockIdx.x * 128;         // 128 cols per block

    // ---- issue ALL label loads first (16 float4 per thread, no deps) ----
    const float* labp[2] = {
        label + (size_t)(i0 + ln) * NN + jbase,
        label + (size_t)(i0 + 16 + ln) * NN + jbase
    };
    floatx4 lb[2][2][4];   // [js][rg][cg]
    #pragma unroll
    for (int js = 0; js < 2; ++js)
        #pragma unroll
        for (int cg = 0; cg < 4; ++cg) {
            const int c4 = js * 64 + cg * 16 + q * 4;
            lb[js][0][cg] = *reinterpret_cast<const floatx4*>(&labp[0][c4]);
            lb[js][1][cg] = *reinterpret_cast<const floatx4*>(&labp[1][c4]);
        }

    // per-block reciprocals: sum 32 partials, one divide per thread
    if (tid < 128) {
        const int row = blockIdx.y * 128 + tid;
        float s = 0.f;
        #pragma unroll 8
        for (int b = 0; b < 32; ++b) s += rowp[(size_t)b * NN + row];
        Rr[tid] = 1.0f / s;
    } else {
        const int col = jbase + tid - 128;
        float s = 0.f;
        #pragma unroll 8
        for (int b = 0; b < 32; ++b) s += colp[(size_t)b * NN + col];
        Rc[tid - 128] = 1.0f / s;
    }

    // stage B rows [jbase, jbase+128) fp32 -> bf16, swizzled 16B slots
    {
        const float* srcb = B + (size_t)jbase * MM;
        char* d = reinterpret_cast<char*>(Bs);
        #pragma unroll
        for (int u = 0; u < 8; ++u) {
            int ch = u * 256 + tid;
            int row = ch >> 4, slot = ch & 15;
            bf16x8 t;
            CVT8(t, srcb + row * MM + slot * 8);
            *reinterpret_cast<bf16x8*>(d + row * 256 + ((slot ^ (row & 7)) << 4)) = t;
        }
    }

    const floatx4 accInit = {-SHIFT, -SHIFT, -SHIFT, -SHIFT};

    bf16x8 a[2][4];
    #pragma unroll
    for (int rg = 0; rg < 2; ++rg) {
        const float* ap = A + (size_t)(i0 + rg * 16 + ln) * MM + q * 8;
        #pragma unroll
        for (int k = 0; k < 4; ++k)
            CVT8(a[rg][k], ap + k * 32);
    }
    __syncthreads();

    const float rl[2] = { Rr[w * 32 + ln], Rr[w * 32 + 16 + ln] };

    const char* bsc = reinterpret_cast<const char*>(Bs);
    const int sw = ln & 7;
    float lacc = 0.f;
    #pragma unroll
    for (int js = 0; js < 2; ++js) {
        const int j0 = js * 64;
        #pragma unroll
        for (int cg = 0; cg < 4; ++cg) {
            // rc broadcast from LDS (same addr within q-group -> conflict-free)
            const floatx4 rc = *reinterpret_cast<const floatx4*>(&Rc[j0 + cg * 16 + q * 4]);
            const char* bp = bsc + (j0 + cg * 16 + ln) * 256;   // (j0+cg*16)&7==0
            bf16x8 b[4];
            #pragma unroll
            for (int k = 0; k < 4; ++k)
                b[k] = *reinterpret_cast<const bf16x8*>(bp + (((q + 4 * k) ^ sw) << 4));
            floatx4 acc0 = accInit, acc1 = accInit;
            #pragma unroll
            for (int k = 0; k < 4; ++k) {
                acc0 = __builtin_amdgcn_mfma_f32_16x16x32_bf16(b[k], a[0][k], acc0, 0, 0, 0);
                acc1 = __builtin_amdgcn_mfma_f32_16x16x32_bf16(b[k], a[1][k], acc1, 0, 0, 0);
            }
            #pragma unroll
            for (int r = 0; r < 4; ++r) {
                float e0 = __expf(acc0[r]);
                float t0 = __logf(fmaf(e0, rl[0], EPSF) * fmaf(e0, rc[r], EPSF));
                lacc = fmaf(lb[js][0][cg][r], t0, lacc);
                float e1 = __expf(acc1[r]);
                float t1 = __logf(fmaf(e1, rl[1], EPSF) * fmaf(e1, rc[r], EPSF));
                lacc = fmaf(lb[js][1][cg][r], t1, lacc);
            }
        }
    }

    #pragma unroll
    for (int m = 1; m <= 32; m <<= 1) lacc += __shfl_xor(lacc, m);
    if (lane == 0) red[w] = lacc;
    __syncthreads();
    if (tid == 0) atomicAdd(out, -((red[0] + red[1]) + (red[2] + red[3])));
}

extern "C" void kernel_launch(void* const* d_in, const int* in_sizes, int n_in,
                              void* d_out, int out_size, void* d_ws, size_t ws_size,
                              hipStream_t stream) {
    const float* out1 = (const float*)d_in[0];
    const float* out2 = (const float*)d_in[1];
    const float* label = (const float*)d_in[2];

    float* rowp = (float*)d_ws;            // 32 x NN floats (1 MB)
    float* colp = rowp + 32 * NN;          // 32 x NN floats (1 MB)

    // no memset needed: partials are pure stores; d_out zeroed in sums_kernel

    // S = out2 @ out1^T -> row/col partials (+ even-band label prefetch)
    sums_kernel<<<dim3(32, 32), 256, 0, stream>>>(out2, out1, label,
                                                  rowp, colp, (float*)d_out);

    // loss pass: partial-sum recips, hoisted label loads, B via swizzled LDS
    loss_kernel<<<dim3(64, 64), 256, 0, stream>>>(out2, out1, rowp, colp,
                                                  label, (float*)d_out);
}